// Round 1
// baseline (900.520 us; speedup 1.0000x reference)
//
#include <hip/hip_runtime.h>
#include <math.h>

#define D 128
#define S 256
#define ROWS 64          // rows per block
#define SCH 64           // negatives per LDS chunk
#define DH 64            // d-extent per LDS chunk (half of D)
#define NCHUNK (S / SCH) // 4

// XOR swizzle: store word d of row r at (d ^ (((r>>2)&7)*4)).
// Keeps float4 groups contiguous & aligned; spreads bank quads across
// the 4 (rows) / 16 (negs) distinct addresses a wave reads -> conflict-free.
__device__ __forceinline__ int swz(int r, int d) {
  return d ^ (((r >> 2) & 7) << 2);
}

__global__ void neg_norm_kernel(const float* __restrict__ emb,
                                const int* __restrict__ negidx,
                                float* __restrict__ negnorm) {
  int s = blockIdx.x;       // 0..S-1
  int lane = threadIdx.x;   // 0..63
  long idx = (long)negidx[s];
  float2 v = *(const float2*)(emb + idx * D + lane * 2);
  float ss = v.x * v.x + v.y * v.y;
#pragma unroll
  for (int off = 1; off < 64; off <<= 1) ss += __shfl_xor(ss, off);
  float inv = 1.0f / fmaxf(sqrtf(ss), 1e-8f);   // cosine_similarity eps
  float2 o = make_float2(v.x * inv, v.y * inv);
  *(float2*)(negnorm + s * D + lane * 2) = o;
}

__global__ __launch_bounds__(256, 2)
void hyper_main(const float* __restrict__ emb,
                const int* __restrict__ posidx,
                const float* __restrict__ negnorm,
                double* __restrict__ acc,
                int N) {
  __shared__ float rows_s[ROWS * D];   // 32 KB, swizzled
  __shared__ float negs_s[SCH * DH];   // 16 KB, swizzled
  __shared__ float ss_s[ROWS];
  __shared__ float invc10_s[ROWS];     // 10/max(||x||,1e-8)  (logit scale fused)
  __shared__ float inv12_s[ROWS];      // 1/max(||x||,1e-12)
  __shared__ float red_s[4];

  const int t = threadIdx.x;
  const int rbase = blockIdx.x * ROWS;
  const int w = t >> 6;       // wave id 0..3
  const int lane = t & 63;

  if (t < ROWS) ss_s[t] = 0.0f;
  __syncthreads();

  // ---- load row tile (coalesced float4) + per-row sum of squares ----
#pragma unroll
  for (int k = 0; k < 8; ++k) {
    int flat4 = k * 256 + t;       // [0, 2048) float4 slots, 32 per row
    int r = flat4 >> 5;
    int c4 = flat4 & 31;
    int n = rbase + r;
    float4 v = make_float4(0.f, 0.f, 0.f, 0.f);
    if (n < N) v = *(const float4*)(emb + (long)n * D + c4 * 4);
    *(float4*)&rows_s[r * D + swz(r, c4 * 4)] = v;
    float p = v.x * v.x + v.y * v.y + v.z * v.z + v.w * v.w;
#pragma unroll
    for (int off = 1; off < 32; off <<= 1) p += __shfl_xor(p, off);
    if ((t & 31) == 0) atomicAdd(&ss_s[r], p);
  }
  __syncthreads();

  if (t < ROWS) {
    float nrm = sqrtf(ss_s[t]);
    invc10_s[t] = 10.0f / fmaxf(nrm, 1e-8f);
    inv12_s[t]  = 1.0f  / fmaxf(nrm, 1e-12f);
  }
  __syncthreads();

  // ---- prefetch positive-pair gathers (consumed after the neg loop) ----
  float2 px[16];
#pragma unroll
  for (int i = 0; i < 16; ++i) {
    int n = rbase + w * 16 + i;
    float2 v = make_float2(0.f, 0.f);
    if (n < N) {
      long p = (long)posidx[n];
      v = *(const float2*)(emb + p * D + lane * 2);
    }
    px[i] = v;
  }

  // ---- negatives: 4 chunks of 64 negs, each in two 64-d halves ----
  const int ty = t >> 4;         // 0..15 -> rows ty*4..ty*4+3
  const int tx = t & 15;         // 0..15 -> negs tx*4..tx*4+3
  const int ty4 = ty * 4, tx4 = tx * 4;
  const int amask = (ty & 7) << 2;
  const int bmask = (tx & 7) << 2;

  float sc[4];
#pragma unroll
  for (int i = 0; i < 4; ++i) sc[i] = invc10_s[ty4 + i];

  float mrun[4], lrun[4];
#pragma unroll
  for (int i = 0; i < 4; ++i) { mrun[i] = -INFINITY; lrun[i] = 0.f; }

  for (int c = 0; c < NCHUNK; ++c) {
    float accm[4][4];
#pragma unroll
    for (int i = 0; i < 4; ++i)
#pragma unroll
      for (int j = 0; j < 4; ++j) accm[i][j] = 0.f;

    for (int h = 0; h < 2; ++h) {
      __syncthreads();   // previous chunk fully consumed
#pragma unroll
      for (int k = 0; k < 4; ++k) {
        int flat4 = k * 256 + t;     // [0,1024): 64 negs x 16 quads
        int srow = flat4 >> 4;
        int c4 = flat4 & 15;
        float4 v = *(const float4*)(negnorm + (c * SCH + srow) * D + h * DH + c4 * 4);
        *(float4*)&negs_s[srow * DH + swz(srow, c4 * 4)] = v;
      }
      __syncthreads();

#pragma unroll 8
      for (int d2 = 0; d2 < DH; d2 += 4) {
        int oa = h * DH + (d2 ^ amask);
        int ob = d2 ^ bmask;
        float4 a0 = *(const float4*)&rows_s[(ty4 + 0) * D + oa];
        float4 a1 = *(const float4*)&rows_s[(ty4 + 1) * D + oa];
        float4 a2 = *(const float4*)&rows_s[(ty4 + 2) * D + oa];
        float4 a3 = *(const float4*)&rows_s[(ty4 + 3) * D + oa];
        float4 b0 = *(const float4*)&negs_s[(tx4 + 0) * DH + ob];
        float4 b1 = *(const float4*)&negs_s[(tx4 + 1) * DH + ob];
        float4 b2 = *(const float4*)&negs_s[(tx4 + 2) * DH + ob];
        float4 b3 = *(const float4*)&negs_s[(tx4 + 3) * DH + ob];
        float4 A[4] = {a0, a1, a2, a3};
        float4 B[4] = {b0, b1, b2, b3};
#pragma unroll
        for (int i = 0; i < 4; ++i)
#pragma unroll
          for (int j = 0; j < 4; ++j) {
            accm[i][j] = fmaf(A[i].x, B[j].x, accm[i][j]);
            accm[i][j] = fmaf(A[i].y, B[j].y, accm[i][j]);
            accm[i][j] = fmaf(A[i].z, B[j].z, accm[i][j]);
            accm[i][j] = fmaf(A[i].w, B[j].w, accm[i][j]);
          }
      }
    }

    // fold this chunk's 4 logits/row into running (m,l)
#pragma unroll
    for (int i = 0; i < 4; ++i) {
      float lg0 = accm[i][0] * sc[i];
      float lg1 = accm[i][1] * sc[i];
      float lg2 = accm[i][2] * sc[i];
      float lg3 = accm[i][3] * sc[i];
      float mc = fmaxf(fmaxf(lg0, lg1), fmaxf(lg2, lg3));
      float mn = fmaxf(mrun[i], mc);
      lrun[i] = lrun[i] * expf(mrun[i] - mn)
              + expf(lg0 - mn) + expf(lg1 - mn)
              + expf(lg2 - mn) + expf(lg3 - mn);
      mrun[i] = mn;
    }
  }

  // ---- combine (m,l) across the 16 tx lanes (contiguous lane groups) ----
  float negsum = 0.f;
#pragma unroll
  for (int i = 0; i < 4; ++i) {
    float mi = mrun[i], li = lrun[i];
#pragma unroll
    for (int off = 1; off < 16; off <<= 1) {
      float mo = __shfl_xor(mi, off);
      float lo = __shfl_xor(li, off);
      float mn = fmaxf(mi, mo);
      li = li * expf(mi - mn) + lo * expf(mo - mn);
      mi = mn;
    }
    if (tx == 0) {
      int n = rbase + ty4 + i;
      if (n < N) negsum += mi + logf(li) - 5.545177444479562f; // log(256)
    }
  }

  // ---- positive pairs: one row per wave-iteration, shuffle reduce ----
  float possum = 0.f;
#pragma unroll
  for (int i = 0; i < 16; ++i) {
    int r = w * 16 + i;
    int n = rbase + r;
    int dw = (2 * lane) ^ (((r >> 2) & 7) << 2);
    float2 xr = *(const float2*)&rows_s[r * D + dw];
    float2 vp = px[i];
    float dp = xr.x * vp.x + xr.y * vp.y;
    float sp = vp.x * vp.x + vp.y * vp.y;
#pragma unroll
    for (int off = 1; off < 64; off <<= 1) {
      dp += __shfl_xor(dp, off);
      sp += __shfl_xor(sp, off);
    }
    if (lane == 0 && n < N) {
      float invp = 1.0f / fmaxf(sqrtf(sp), 1e-12f);
      possum += dp * inv12_s[r] * invp * 10.0f;
    }
  }

  // ---- block reduce -> one double atomic per block ----
  float local = negsum - possum;
#pragma unroll
  for (int off = 1; off < 64; off <<= 1) local += __shfl_xor(local, off);
  if (lane == 0) red_s[w] = local;
  __syncthreads();
  if (t == 0) {
    double tot = (double)red_s[0] + (double)red_s[1] +
                 (double)red_s[2] + (double)red_s[3];
    atomicAdd(acc, tot);
  }
}

__global__ void finish_kernel(const double* __restrict__ acc,
                              float* __restrict__ out, int N) {
  out[0] = (float)(acc[0] / (double)N);
}

extern "C" void kernel_launch(void* const* d_in, const int* in_sizes, int n_in,
                              void* d_out, int out_size, void* d_ws, size_t ws_size,
                              hipStream_t stream) {
  const float* emb   = (const float*)d_in[0];
  const int* posidx  = (const int*)d_in[1];
  const int* negidx  = (const int*)d_in[2];
  int N = in_sizes[1];

  double* acc = (double*)d_ws;
  float* negnorm = (float*)((char*)d_ws + 256);

  hipMemsetAsync(d_ws, 0, 256, stream);
  neg_norm_kernel<<<S, 64, 0, stream>>>(emb, negidx, negnorm);
  int grid = (N + ROWS - 1) / ROWS;
  hyper_main<<<grid, 256, 0, stream>>>(emb, posidx, negnorm, acc, N);
  finish_kernel<<<1, 1, 0, stream>>>(acc, (float*)d_out, N);
}

// Round 2
// 496.927 us; speedup vs baseline: 1.8122x; 1.8122x over previous
//
#include <hip/hip_runtime.h>
#include <hip/hip_bf16.h>
#include <math.h>

#define D 128
#define S 256
#define ROWS 64
#define NEG_CHUNK 128
#define LOG_S 5.545177444479562f

typedef __attribute__((ext_vector_type(8)))  short    short8;
typedef __attribute__((ext_vector_type(8)))  __bf16   bf16x8;
typedef __attribute__((ext_vector_type(16))) float    floatx16;

__device__ __forceinline__ unsigned short f2bf(float x) {
  __hip_bfloat16 h = __float2bfloat16(x);   // RNE
  return *(unsigned short*)&h;
}

// ---- normalize the 256 negative rows (eps=1e-8) -> bf16 [S][D] ----
__global__ void neg_norm_kernel(const float* __restrict__ emb,
                                const int* __restrict__ negidx,
                                unsigned short* __restrict__ negbf) {
  int s = blockIdx.x;       // 0..S-1
  int lane = threadIdx.x;   // 0..63
  long idx = (long)negidx[s];
  float2 v = *(const float2*)(emb + idx * D + lane * 2);
  float ss = v.x * v.x + v.y * v.y;
#pragma unroll
  for (int off = 1; off < 64; off <<= 1) ss += __shfl_xor(ss, off);
  float inv = 1.0f / fmaxf(sqrtf(ss), 1e-8f);
  unsigned short o0 = f2bf(v.x * inv), o1 = f2bf(v.y * inv);
  ushort2 o = make_ushort2(o0, o1);
  *(ushort2*)(negbf + s * D + lane * 2) = o;
}

// LDS (48 KB): rows bf16 [64][128] swizzled @0 (16 KB), negs bf16 [128][128]
// swizzled @16K (32 KB). 16B-unit XOR swizzle: unit u = lu ^ (row & 15).
// After MFMA, rows region is reused for (m,l) merge + block reduce.
__global__ __launch_bounds__(256, 3)
void hyper_main(const float* __restrict__ emb,
                const int* __restrict__ posidx,
                const unsigned short* __restrict__ negbf,
                double* __restrict__ acc,
                int N) {
  __shared__ __align__(16) char smem[49152];
  unsigned short* rows_l = (unsigned short*)smem;            // bf16 units
  unsigned short* negs_l = (unsigned short*)(smem + 16384);

  const int t = threadIdx.x;
  const long rbase = (long)blockIdx.x * ROWS;

  // ---- staging: rows -> bf16 LDS, + fused fp32 positive path ----
  float possum = 0.f;
#pragma unroll
  for (int k = 0; k < 8; ++k) {
    int flat4 = k * 256 + t;        // [0,2048): 64 rows x 32 float4
    int r  = flat4 >> 5;            // block row 0..63
    int c4 = flat4 & 31;
    long n = rbase + r;
    bool valid = (n < (long)N);
    float4 v = make_float4(0.f, 0.f, 0.f, 0.f);
    float4 p = make_float4(0.f, 0.f, 0.f, 0.f);
    if (valid) {
      v = *(const float4*)(emb + n * D + c4 * 4);
      long pi = (long)posidx[n];
      p = *(const float4*)(emb + pi * D + c4 * 4);
    }
    float ssv = v.x*v.x + v.y*v.y + v.z*v.z + v.w*v.w;
    float ssp = p.x*p.x + p.y*p.y + p.z*p.z + p.w*p.w;
    float dp  = v.x*p.x + v.y*p.y + v.z*p.z + v.w*p.w;
#pragma unroll
    for (int off = 1; off < 32; off <<= 1) {   // 32-lane group = one row
      ssv += __shfl_xor(ssv, off);
      ssp += __shfl_xor(ssp, off);
      dp  += __shfl_xor(dp,  off);
    }
    float inv8 = 1.0f / fmaxf(sqrtf(ssv), 1e-8f);  // cosine path eps
    ushort4 o = make_ushort4(f2bf(v.x*inv8), f2bf(v.y*inv8),
                             f2bf(v.z*inv8), f2bf(v.w*inv8));
    int u = (c4 >> 1) ^ (r & 15);
    *(ushort4*)&rows_l[r * 128 + u * 8 + (c4 & 1) * 4] = o;
    if ((t & 31) == 0 && valid) {
      float invv = 1.0f / fmaxf(sqrtf(ssv), 1e-12f);  // F.normalize eps
      float invp = 1.0f / fmaxf(sqrtf(ssp), 1e-12f);
      possum += dp * invv * invp * 10.0f;
    }
  }

  // ---- MFMA over negatives: 2 chunks of 128 ----
  const int lane = t & 63;
  const int w  = t >> 6;        // wave 0..3
  const int q  = lane >> 5;     // half-wave
  const int ln = lane & 31;
  const int tr  = w >> 1;       // row tile: rows tr*32..+31
  const int chh = w & 1;        // column half of the chunk
  const int arow = tr * 32 + ln;
  const int nrow0 = chh * 64 + ln;
  const int nrow1 = chh * 64 + 32 + ln;

  float mrun[16], lrun[16];
#pragma unroll
  for (int i = 0; i < 16; ++i) { mrun[i] = -INFINITY; lrun[i] = 0.f; }

  for (int c = 0; c < 2; ++c) {
    __syncthreads();   // rows staged (c=0) / previous chunk consumed (c=1)
#pragma unroll
    for (int k2 = 0; k2 < 8; ++k2) {
      int flat = k2 * 256 + t;       // [0,2048): 128 negs x 16 units
      int nr = flat >> 4;
      int lu = flat & 15;
      uint4 d = *(const uint4*)(negbf + (c * NEG_CHUNK + nr) * D + lu * 8);
      int u = lu ^ (nr & 15);
      *(uint4*)&negs_l[nr * 128 + u * 8] = d;
    }
    __syncthreads();

    floatx16 acc0 = {};
    floatx16 acc1 = {};
#pragma unroll
    for (int ki = 0; ki < 8; ++ki) {
      int lu = ki * 2 + q;
      short8 a  = *(const short8*)&rows_l[arow * 128 + (lu ^ (arow & 15)) * 8];
      short8 b0 = *(const short8*)&negs_l[nrow0 * 128 + (lu ^ (nrow0 & 15)) * 8];
      short8 b1 = *(const short8*)&negs_l[nrow1 * 128 + (lu ^ (nrow1 & 15)) * 8];
      acc0 = __builtin_amdgcn_mfma_f32_32x32x16_bf16(
          __builtin_bit_cast(bf16x8, a), __builtin_bit_cast(bf16x8, b0), acc0, 0, 0, 0);
      acc1 = __builtin_amdgcn_mfma_f32_32x32x16_bf16(
          __builtin_bit_cast(bf16x8, a), __builtin_bit_cast(bf16x8, b1), acc1, 0, 0, 0);
    }

    // fold 2 logits/row-slot into running (m,l)
#pragma unroll
    for (int rg = 0; rg < 16; ++rg) {
      float lg0 = acc0[rg] * 10.f;
      float lg1 = acc1[rg] * 10.f;
      float mc = fmaxf(lg0, lg1);
      float mn = fmaxf(mrun[rg], mc);
      lrun[rg] = lrun[rg] * __expf(mrun[rg] - mn)
               + __expf(lg0 - mn) + __expf(lg1 - mn);
      mrun[rg] = mn;
    }
  }

  // ---- combine (m,l) across the 32 lanes of each half-wave ----
#pragma unroll
  for (int rg = 0; rg < 16; ++rg) {
    float mi = mrun[rg], li = lrun[rg];
#pragma unroll
    for (int off = 1; off < 32; off <<= 1) {
      float mo = __shfl_xor(mi, off);
      float lo = __shfl_xor(li, off);
      float mn = fmaxf(mi, mo);
      li = li * __expf(mi - mn) + lo * __expf(mo - mn);
      mi = mn;
    }
    mrun[rg] = mi; lrun[rg] = li;
  }

  // ---- merge the two column-half waves via LDS (reuse rows region) ----
  __syncthreads();                    // all LDS reads done; safe to reuse
  float2* mlbuf = (float2*)smem;      // [64 rows][2 halves]
  if (ln == 0) {
#pragma unroll
    for (int rg = 0; rg < 16; ++rg) {
      int r = tr * 32 + (rg & 3) + 8 * (rg >> 2) + 4 * q;
      mlbuf[r * 2 + chh] = make_float2(mrun[rg], lrun[rg]);
    }
  }
  __syncthreads();

  float negterm = 0.f;
  if (t < 64) {
    long n = rbase + t;
    if (n < (long)N) {
      float2 a = mlbuf[t * 2 + 0];
      float2 b = mlbuf[t * 2 + 1];
      float mn = fmaxf(a.x, b.x);
      float l = a.y * __expf(a.x - mn) + b.y * __expf(b.x - mn);
      negterm = mn + __logf(l) - LOG_S;
    }
  }

  // ---- block reduce -> one double atomic ----
  float local = negterm - possum;
#pragma unroll
  for (int off = 1; off < 64; off <<= 1) local += __shfl_xor(local, off);
  float* red = (float*)(smem + 2048);
  if (lane == 0) red[w] = local;
  __syncthreads();
  if (t == 0) {
    double tot = (double)red[0] + (double)red[1] +
                 (double)red[2] + (double)red[3];
    atomicAdd(acc, tot);
  }
}

__global__ void finish_kernel(const double* __restrict__ acc,
                              float* __restrict__ out, int N) {
  out[0] = (float)(acc[0] / (double)N);
}

extern "C" void kernel_launch(void* const* d_in, const int* in_sizes, int n_in,
                              void* d_out, int out_size, void* d_ws, size_t ws_size,
                              hipStream_t stream) {
  const float* emb  = (const float*)d_in[0];
  const int* posidx = (const int*)d_in[1];
  const int* negidx = (const int*)d_in[2];
  int N = in_sizes[1];

  double* acc = (double*)d_ws;
  unsigned short* negbf = (unsigned short*)((char*)d_ws + 256);

  hipMemsetAsync(d_ws, 0, 256, stream);
  neg_norm_kernel<<<S, 64, 0, stream>>>(emb, negidx, negbf);
  int grid = (N + ROWS - 1) / ROWS;
  hyper_main<<<grid, 256, 0, stream>>>(emb, posidx, negbf, acc, N);
  finish_kernel<<<1, 1, 0, stream>>>(acc, (float*)d_out, N);
}

// Round 3
// 411.849 us; speedup vs baseline: 2.1865x; 1.2066x over previous
//
#include <hip/hip_runtime.h>
#include <hip/hip_bf16.h>
#include <math.h>

#define D 128
#define S 256
#define ROWS 64
#define LOG_S 5.545177444479562f

typedef __attribute__((ext_vector_type(8)))  short    short8;
typedef __attribute__((ext_vector_type(8)))  __bf16   bf16x8;
typedef __attribute__((ext_vector_type(16))) float    floatx16;

typedef const __attribute__((address_space(1))) void gas_void;
typedef __attribute__((address_space(3))) void las_void;

__device__ __forceinline__ unsigned short f2bf(float x) {
  __hip_bfloat16 h = __float2bfloat16(x);   // RNE
  return *(unsigned short*)&h;
}

// ---- normalize negatives (eps=1e-8), fold 1/T=10, emit PRE-SWIZZLED bf16 ----
// Global layout = the LDS image hyper_main wants: chunk c (128 negs) occupies
// 16384 shorts; neg nr stores its 16B-unit lu at unit (lu ^ (nr&15)).
__global__ void neg_norm_kernel(const float* __restrict__ emb,
                                const int* __restrict__ negidx,
                                unsigned short* __restrict__ negsw) {
  int s = blockIdx.x;       // 0..S-1
  int L = threadIdx.x;      // 0..63, elements 2L,2L+1
  long idx = (long)negidx[s];
  float2 v = *(const float2*)(emb + idx * D + L * 2);
  float ss = v.x * v.x + v.y * v.y;
#pragma unroll
  for (int off = 1; off < 64; off <<= 1) ss += __shfl_xor(ss, off);
  float sc = 10.0f / fmaxf(sqrtf(ss), 1e-8f);
  int chunk = s >> 7, nr = s & 127;
  int lu = L >> 2, pos = (L & 3) * 2;
  int u = lu ^ (nr & 15);
  ushort2 o = make_ushort2(f2bf(v.x * sc), f2bf(v.y * sc));
  *(ushort2*)(negsw + chunk * 16384 + nr * 128 + u * 8 + pos) = o;
}

// LDS 48 KB: rows bf16 [64][128] swizzled @0, negs chunk [128][128] @16K.
__global__ __launch_bounds__(256, 3)
void hyper_main(const float* __restrict__ emb,
                const int* __restrict__ posidx,
                const unsigned short* __restrict__ negsw,
                double* __restrict__ acc,
                int N) {
  __shared__ __align__(16) char smem[49152];
  unsigned short* rows_l = (unsigned short*)smem;
  unsigned short* negs_l = (unsigned short*)(smem + 16384);

  const int t = threadIdx.x;
  const int lane = t & 63;
  const int w = t >> 6;
  const long rbase = (long)blockIdx.x * ROWS;

  // ---- issue chunk-0 negative staging immediately (async, in flight
  //      during the entire row-staging pass) ----
  {
    const char* g = (const char*)negsw + w * 8192 + lane * 16;
    char* l = (char*)negs_l + w * 8192;
#pragma unroll
    for (int i = 0; i < 8; ++i)
      __builtin_amdgcn_global_load_lds((gas_void*)(g + i * 1024),
                                       (las_void*)(l + i * 1024), 16, 0, 0);
  }

  // ---- stage rows: thread owns row t>>2, quarter t&3; register-accumulate
  //      ssv/ssp/dp, ONE 4-lane reduce at the end ----
  const int r  = t >> 2;
  const int qq = t & 3;
  long n = rbase + r;
  bool valid = (n < (long)N);
  long pi = 0;
  if (valid) pi = (long)posidx[n];

  float4 v[8];
  float ssv = 0.f, ssp = 0.f, dp = 0.f;
#pragma unroll
  for (int k = 0; k < 8; ++k) {
    int c4 = qq + 4 * k;
    float4 vv = make_float4(0.f, 0.f, 0.f, 0.f);
    float4 pp = make_float4(0.f, 0.f, 0.f, 0.f);
    if (valid) {
      vv = *(const float4*)(emb + n * D + c4 * 4);
      pp = *(const float4*)(emb + pi * D + c4 * 4);
    }
    v[k] = vv;
    ssv += vv.x*vv.x + vv.y*vv.y + vv.z*vv.z + vv.w*vv.w;
    ssp += pp.x*pp.x + pp.y*pp.y + pp.z*pp.z + pp.w*pp.w;
    dp  += vv.x*pp.x + vv.y*pp.y + vv.z*pp.z + vv.w*pp.w;
  }
#pragma unroll
  for (int off = 1; off < 4; off <<= 1) {
    ssv += __shfl_xor(ssv, off);
    ssp += __shfl_xor(ssp, off);
    dp  += __shfl_xor(dp,  off);
  }
  float inv8 = 1.0f / fmaxf(sqrtf(ssv), 1e-8f);   // cosine-path eps
#pragma unroll
  for (int k = 0; k < 8; ++k) {
    int c4 = qq + 4 * k;
    int u = (c4 >> 1) ^ (r & 15);
    ushort4 o = make_ushort4(f2bf(v[k].x*inv8), f2bf(v[k].y*inv8),
                             f2bf(v[k].z*inv8), f2bf(v[k].w*inv8));
    *(ushort4*)&rows_l[r * 128 + u * 8 + (c4 & 1) * 4] = o;
  }
  float possum = 0.f;
  if (qq == 0 && valid) {
    float invv = 1.0f / fmaxf(sqrtf(ssv), 1e-12f);  // F.normalize eps
    float invp = 1.0f / fmaxf(sqrtf(ssp), 1e-12f);
    possum = dp * invv * invp * 10.0f;
  }

  // ---- MFMA over negatives: 2 chunks of 128, plain exp-sum (bounded
  //      logits: |lg|<=10 -> no overflow, no online softmax needed) ----
  const int q   = lane >> 5;
  const int ln  = lane & 31;
  const int tr  = w >> 1;
  const int chh = w & 1;
  const int arow  = tr * 32 + ln;
  const int nrow0 = chh * 64 + ln;
  const int nrow1 = nrow0 + 32;

  float se[16];
#pragma unroll
  for (int i = 0; i < 16; ++i) se[i] = 0.f;

  for (int c = 0; c < 2; ++c) {
    __syncthreads();   // staged data visible (drains global_load_lds too)
    floatx16 acc0 = {};
    floatx16 acc1 = {};
#pragma unroll
    for (int ki = 0; ki < 8; ++ki) {
      int lu = ki * 2 + q;
      short8 a  = *(const short8*)&rows_l[arow  * 128 + (lu ^ (arow  & 15)) * 8];
      short8 b0 = *(const short8*)&negs_l[nrow0 * 128 + (lu ^ (nrow0 & 15)) * 8];
      short8 b1 = *(const short8*)&negs_l[nrow1 * 128 + (lu ^ (nrow1 & 15)) * 8];
      acc0 = __builtin_amdgcn_mfma_f32_32x32x16_bf16(
          __builtin_bit_cast(bf16x8, a), __builtin_bit_cast(bf16x8, b0), acc0, 0, 0, 0);
      acc1 = __builtin_amdgcn_mfma_f32_32x32x16_bf16(
          __builtin_bit_cast(bf16x8, a), __builtin_bit_cast(bf16x8, b1), acc1, 0, 0, 0);
    }
    if (c == 0) {
      __syncthreads();   // everyone done reading chunk 0 -> safe to overwrite
      const char* g = (const char*)negsw + 32768 + w * 8192 + lane * 16;
      char* l = (char*)negs_l + w * 8192;
#pragma unroll
      for (int i = 0; i < 8; ++i)
        __builtin_amdgcn_global_load_lds((gas_void*)(g + i * 1024),
                                         (las_void*)(l + i * 1024), 16, 0, 0);
    }
#pragma unroll
    for (int rg = 0; rg < 16; ++rg)
      se[rg] += __expf(acc0[rg]) + __expf(acc1[rg]);
  }

  // ---- combine exp-sums across the 32 lanes of each half-wave (adds only) ----
#pragma unroll
  for (int rg = 0; rg < 16; ++rg) {
    float sv = se[rg];
#pragma unroll
    for (int off = 1; off < 32; off <<= 1) sv += __shfl_xor(sv, off);
    se[rg] = sv;
  }

  // ---- merge the two column-half waves via LDS (reuse rows region) ----
  __syncthreads();
  float* sebuf = (float*)smem;   // [64 rows][2 halves]
  if (ln == 0) {
#pragma unroll
    for (int rg = 0; rg < 16; ++rg) {
      int rr = tr * 32 + (rg & 3) + 8 * (rg >> 2) + 4 * q;
      sebuf[rr * 2 + chh] = se[rg];
    }
  }
  __syncthreads();

  float negterm = 0.f;
  if (t < 64) {
    long n2 = rbase + t;
    if (n2 < (long)N)
      negterm = __logf(sebuf[t * 2] + sebuf[t * 2 + 1]) - LOG_S;
  }

  // ---- block reduce -> one double atomic ----
  float local = negterm - possum;
#pragma unroll
  for (int off = 1; off < 64; off <<= 1) local += __shfl_xor(local, off);
  float* red = (float*)(smem + 2048);
  if (lane == 0) red[w] = local;
  __syncthreads();
  if (t == 0) {
    double tot = (double)red[0] + (double)red[1] +
                 (double)red[2] + (double)red[3];
    atomicAdd(acc, tot);
  }
}

__global__ void finish_kernel(const double* __restrict__ acc,
                              float* __restrict__ out, int N) {
  out[0] = (float)(acc[0] / (double)N);
}

extern "C" void kernel_launch(void* const* d_in, const int* in_sizes, int n_in,
                              void* d_out, int out_size, void* d_ws, size_t ws_size,
                              hipStream_t stream) {
  const float* emb  = (const float*)d_in[0];
  const int* posidx = (const int*)d_in[1];
  const int* negidx = (const int*)d_in[2];
  int N = in_sizes[1];

  double* acc = (double*)d_ws;
  unsigned short* negsw = (unsigned short*)((char*)d_ws + 256);

  hipMemsetAsync(d_ws, 0, 256, stream);
  neg_norm_kernel<<<S, 64, 0, stream>>>(emb, negidx, negsw);
  int grid = (N + ROWS - 1) / ROWS;
  hyper_main<<<grid, 256, 0, stream>>>(emb, posidx, negsw, acc, N);
  finish_kernel<<<1, 1, 0, stream>>>(acc, (float*)d_out, N);
}